// Round 2
// baseline (757.710 us; speedup 1.0000x reference)
//
#include <hip/hip_runtime.h>
#include <hip/hip_bf16.h>

#define B_ 2
#define S_ 2048
#define H_ 2048
#define NH_ 16
#define HD_ 128
#define M_ (B_*S_)   // 4096

typedef unsigned short u16;
typedef __attribute__((ext_vector_type(8))) short bhalf8_t;   // 8 bf16 in 4 VGPRs
typedef __attribute__((ext_vector_type(4))) float fx4_t;      // MFMA accumulator

__device__ __forceinline__ float bf2f(u16 v) {
    unsigned u = ((unsigned)v) << 16;
    return __builtin_bit_cast(float, u);
}
__device__ __forceinline__ u16 f2bf(float f) {
    unsigned u = __builtin_bit_cast(unsigned, f);
    unsigned r = u + 0x7fffu + ((u >> 16) & 1u);   // RNE
    return (u16)(r >> 16);
}

// ---------------- fp32 -> bf16 elementwise convert ---------------------------
__global__ __launch_bounds__(256) void cvt_bf16_k(const float* __restrict__ in,
                                                  u16* __restrict__ out) {
    int i = blockIdx.x * 256 + threadIdx.x;      // one float4 per thread
    float4 v = ((const float4*)in)[i];
    ushort4 o;
    o.x = f2bf(v.x); o.y = f2bf(v.y); o.z = f2bf(v.z); o.w = f2bf(v.w);
    ((ushort4*)out)[i] = o;
}

// -------- weight transpose+convert: out_bf16[n][k] = in_f32[k][n], 2048x2048 --
__global__ __launch_bounds__(256) void transpose_cvt_k(const float* __restrict__ in,
                                                       u16* __restrict__ out) {
    __shared__ u16 tile[64][65];
    int k0 = blockIdx.y * 64, n0 = blockIdx.x * 64;
    int t = threadIdx.x;
    for (int i = 0; i < 16; i++) {
        int idx = t + i * 256;
        int r = idx >> 6, c = idx & 63;
        tile[r][c] = f2bf(in[(size_t)(k0 + r) * H_ + n0 + c]);
    }
    __syncthreads();
    for (int i = 0; i < 16; i++) {
        int idx = t + i * 256;
        int r = idx >> 6, c = idx & 63;
        out[(size_t)(n0 + r) * H_ + k0 + c] = tile[c][r];
    }
}

// ---------------- GEMM: C[M][N] = A[M][K] @ Bt[N][K]^T + bias[N] -------------
// 128x128 tile, 4 waves (2x2 of 64x64), mfma_f32_16x16x32_bf16.
// F32OUT: write fp32 (final O-proj into d_out); else bf16.
template <bool F32OUT>
__global__ __launch_bounds__(256) void gemm_bt_bias(const u16* __restrict__ A,
                                                    const u16* __restrict__ Bt,
                                                    const float* __restrict__ bias,
                                                    void* __restrict__ Cv,
                                                    int Nsz, int Ksz) {
    __shared__ u16 As[128][32];
    __shared__ u16 Bs[128][32];
    int t = threadIdx.x;
    int wave = t >> 6, lane = t & 63;
    int lr = lane & 15, lq = lane >> 4;
    int m0 = blockIdx.y * 128, n0 = blockIdx.x * 128;
    int wm = (wave >> 1) * 64, wn = (wave & 1) * 64;

    fx4_t acc[4][4];
    for (int i = 0; i < 4; i++)
        for (int j = 0; j < 4; j++)
            acc[i][j] = (fx4_t){0.f, 0.f, 0.f, 0.f};

    for (int k0 = 0; k0 < Ksz; k0 += 32) {
        for (int i = 0; i < 2; i++) {
            int chunk = t + i * 256;           // 512 chunks of 8 elems
            int r = chunk >> 2, kc = (chunk & 3) * 8;
            *(bhalf8_t*)&As[r][kc] = *(const bhalf8_t*)&A[(size_t)(m0 + r) * Ksz + k0 + kc];
            *(bhalf8_t*)&Bs[r][kc] = *(const bhalf8_t*)&Bt[(size_t)(n0 + r) * Ksz + k0 + kc];
        }
        __syncthreads();
        bhalf8_t a[4], b[4];
        for (int i = 0; i < 4; i++) a[i] = *(const bhalf8_t*)&As[wm + i * 16 + lr][lq * 8];
        for (int j = 0; j < 4; j++) b[j] = *(const bhalf8_t*)&Bs[wn + j * 16 + lr][lq * 8];
        for (int i = 0; i < 4; i++)
            for (int j = 0; j < 4; j++)
                acc[i][j] = __builtin_amdgcn_mfma_f32_16x16x32_bf16(a[i], b[j], acc[i][j], 0, 0, 0);
        __syncthreads();
    }
    // C/D layout: row=(lane>>4)*4+reg, col=lane&15  [verified m89/m91]
    for (int i = 0; i < 4; i++)
        for (int j = 0; j < 4; j++) {
            int row = m0 + wm + i * 16 + lq * 4;
            int col = n0 + wn + j * 16 + lr;
            float bv = bias[col];
            for (int r = 0; r < 4; r++) {
                float v = acc[i][j][r] + bv;
                if (F32OUT)
                    ((float*)Cv)[(size_t)(row + r) * Nsz + col] = v;
                else
                    ((u16*)Cv)[(size_t)(row + r) * Nsz + col] = f2bf(v);
            }
        }
}

// ---------------- RoPE in-place on q and k ([B,S,NH,HD], bf16) ---------------
__global__ __launch_bounds__(256) void rope_k(u16* __restrict__ q, u16* __restrict__ k) {
    int idx = blockIdx.x * 256 + threadIdx.x;   // B*S*NH*64 threads
    int i = idx & 63;
    int n = (idx >> 6) & 15;
    int s = (idx >> 10) & 2047;
    int b = idx >> 21;
    float inv = 1.0f / powf(10000.0f, (float)i * (1.0f / 64.0f));
    float ang = (float)s * inv;
    float sn, c;
    sincosf(ang, &sn, &c);
    size_t base = ((size_t)(b * S_ + s) * NH_ + n) * HD_ + i;
    {
        float x1 = bf2f(q[base]), x2 = bf2f(q[base + 64]);
        q[base]      = f2bf(x1 * c - x2 * sn);
        q[base + 64] = f2bf(x2 * c + x1 * sn);
    }
    {
        float x1 = bf2f(k[base]), x2 = bf2f(k[base + 64]);
        k[base]      = f2bf(x1 * c - x2 * sn);
        k[base + 64] = f2bf(x2 * c + x1 * sn);
    }
}

// ---------------- flash attention, causal ------------------------------------
// block = (q-tile 64 rows, head, batch); 4 waves, each owns 16 q rows.
__global__ __launch_bounds__(256) void flash_k(const u16* __restrict__ qb,
                                               const u16* __restrict__ kb,
                                               const u16* __restrict__ vb,
                                               u16* __restrict__ attn) {
    __shared__ u16 Qs[64][128];
    __shared__ u16 Ks[64][128];
    __shared__ u16 Vt[128][64];   // Vt[d][kpos]
    __shared__ u16 Ps[64][64];
    int t = threadIdx.x, wave = t >> 6, lane = t & 63;
    int lr = lane & 15, lq = lane >> 4;
    int q0 = blockIdx.x * 64, h = blockIdx.y, b = blockIdx.z;
    const float scale = 0.08838834764831845f;   // 1/sqrt(128)

    for (int i = 0; i < 4; i++) {
        int chunk = t + i * 256;
        int r = chunk >> 4, cg = (chunk & 15) * 8;
        *(bhalf8_t*)&Qs[r][cg] =
            *(const bhalf8_t*)&qb[((size_t)(b * S_ + q0 + r) * NH_ + h) * HD_ + cg];
    }
    float m_i[4], l_i[4];
    fx4_t acc_o[8];
    for (int r = 0; r < 4; r++) { m_i[r] = -INFINITY; l_i[r] = 0.f; }
    for (int dt = 0; dt < 8; dt++) acc_o[dt] = (fx4_t){0.f, 0.f, 0.f, 0.f};

    int nkb = blockIdx.x + 1;   // causal: k-blocks 0..q-block inclusive
    for (int kb0 = 0; kb0 < nkb; kb0++) {
        int k0 = kb0 * 64;
        __syncthreads();   // prev iter's PV done before restaging
        for (int i = 0; i < 4; i++) {
            int chunk = t + i * 256;
            int r = chunk >> 4, cg = (chunk & 15) * 8;
            *(bhalf8_t*)&Ks[r][cg] =
                *(const bhalf8_t*)&kb[((size_t)(b * S_ + k0 + r) * NH_ + h) * HD_ + cg];
        }
        for (int i = 0; i < 4; i++) {
            int chunk = t + i * 256;
            int r = chunk & 63, d0 = (chunk >> 6) * 8;
            bhalf8_t vv =
                *(const bhalf8_t*)&vb[((size_t)(b * S_ + k0 + r) * NH_ + h) * HD_ + d0];
            for (int j = 0; j < 8; j++) Vt[d0 + j][r] = (u16)vv[j];
        }
        __syncthreads();

        // S = Q K^T for this wave's 16 rows x 64 cols
        fx4_t sacc[4];
        for (int nt = 0; nt < 4; nt++) sacc[nt] = (fx4_t){0.f, 0.f, 0.f, 0.f};
        bhalf8_t aq[4];
        for (int ds = 0; ds < 4; ds++)
            aq[ds] = *(const bhalf8_t*)&Qs[wave * 16 + lr][ds * 32 + lq * 8];
        for (int nt = 0; nt < 4; nt++)
            for (int ds = 0; ds < 4; ds++) {
                bhalf8_t bk = *(const bhalf8_t*)&Ks[nt * 16 + lr][ds * 32 + lq * 8];
                sacc[nt] = __builtin_amdgcn_mfma_f32_16x16x32_bf16(aq[ds], bk, sacc[nt], 0, 0, 0);
            }

        // online softmax (fp32). lane holds rows lq*4+r, cols nt*16+lr.
        float sv[4][4];
        for (int nt = 0; nt < 4; nt++)
            for (int r = 0; r < 4; r++) {
                float x = sacc[nt][r] * scale;
                int kpos = k0 + nt * 16 + lr;
                int qpos = q0 + wave * 16 + lq * 4 + r;
                if (kpos > qpos) x -= 1e9f;
                sv[nt][r] = x;
            }
        float rmax[4], alpha[4], rsum[4];
        for (int r = 0; r < 4; r++)
            rmax[r] = fmaxf(fmaxf(sv[0][r], sv[1][r]), fmaxf(sv[2][r], sv[3][r]));
        for (int off = 1; off < 16; off <<= 1)
            for (int r = 0; r < 4; r++)
                rmax[r] = fmaxf(rmax[r], __shfl_xor(rmax[r], off, 64));
        for (int r = 0; r < 4; r++) {
            float mn = fmaxf(m_i[r], rmax[r]);
            alpha[r] = __expf(m_i[r] - mn);
            m_i[r] = mn;
            float s4 = 0.f;
            for (int nt = 0; nt < 4; nt++) {
                float p = __expf(sv[nt][r] - mn);
                sv[nt][r] = p;
                s4 += p;
            }
            rsum[r] = s4;
        }
        for (int off = 1; off < 16; off <<= 1)
            for (int r = 0; r < 4; r++)
                rsum[r] += __shfl_xor(rsum[r], off, 64);
        for (int r = 0; r < 4; r++) l_i[r] = l_i[r] * alpha[r] + rsum[r];
        for (int dt = 0; dt < 8; dt++)
            for (int r = 0; r < 4; r++) acc_o[dt][r] *= alpha[r];

        // P (C-layout) -> LDS -> A-layout for PV
        for (int nt = 0; nt < 4; nt++)
            for (int r = 0; r < 4; r++)
                Ps[wave * 16 + lq * 4 + r][nt * 16 + lr] = f2bf(sv[nt][r]);
        __syncthreads();

        for (int ds = 0; ds < 2; ds++) {
            bhalf8_t ap = *(const bhalf8_t*)&Ps[wave * 16 + lr][ds * 32 + lq * 8];
            for (int dt = 0; dt < 8; dt++) {
                bhalf8_t bv = *(const bhalf8_t*)&Vt[dt * 16 + lr][ds * 32 + lq * 8];
                acc_o[dt] = __builtin_amdgcn_mfma_f32_16x16x32_bf16(ap, bv, acc_o[dt], 0, 0, 0);
            }
        }
    }
    for (int dt = 0; dt < 8; dt++)
        for (int r = 0; r < 4; r++) {
            size_t row = (size_t)(b * S_ + q0 + wave * 16 + lq * 4 + r);
            attn[(row * NH_ + h) * HD_ + dt * 16 + lr] = f2bf(acc_o[dt][r] / l_i[r]);
        }
}

extern "C" void kernel_launch(void* const* d_in, const int* in_sizes, int n_in,
                              void* d_out, int out_size, void* d_ws, size_t ws_size,
                              hipStream_t stream) {
    const float* hs = (const float*)d_in[0];
    // d_in[1] = mask (causal triu) — hard-coded in flash_k
    const float* Wq = (const float*)d_in[2];
    const float* bq = (const float*)d_in[3];
    const float* Wk = (const float*)d_in[4];
    const float* bk = (const float*)d_in[5];
    const float* Wv = (const float*)d_in[6];
    const float* bv = (const float*)d_in[7];
    const float* Wo = (const float*)d_in[8];
    const float* bo = (const float*)d_in[9];
    float* out = (float*)d_out;

    u16* ws   = (u16*)d_ws;
    size_t WW = (size_t)H_ * H_;       // 4.19M elems
    size_t AC = (size_t)M_ * H_;       // 8.39M elems
    u16* hsb  = ws;
    u16* WqT  = hsb + AC;
    u16* WkT  = WqT + WW;
    u16* WvT  = WkT + WW;
    u16* WoT  = WvT + WW;
    u16* qb   = WoT + WW;
    u16* kbuf = qb + AC;
    u16* vbuf = kbuf + AC;
    u16* attn = vbuf + AC;

    dim3 tb(256);

    cvt_bf16_k<<<dim3(AC / (256 * 4)), tb, 0, stream>>>(hs, hsb);

    dim3 gT(32, 32);
    transpose_cvt_k<<<gT, tb, 0, stream>>>(Wq, WqT);
    transpose_cvt_k<<<gT, tb, 0, stream>>>(Wk, WkT);
    transpose_cvt_k<<<gT, tb, 0, stream>>>(Wv, WvT);
    transpose_cvt_k<<<gT, tb, 0, stream>>>(Wo, WoT);

    dim3 gG(H_ / 128, M_ / 128);       // (16, 32)
    gemm_bt_bias<false><<<gG, tb, 0, stream>>>(hsb, WqT, bq, qb, H_, H_);
    gemm_bt_bias<false><<<gG, tb, 0, stream>>>(hsb, WkT, bk, kbuf, H_, H_);
    gemm_bt_bias<false><<<gG, tb, 0, stream>>>(hsb, WvT, bv, vbuf, H_, H_);

    rope_k<<<dim3((B_ * S_ * NH_ * 64) / 256), tb, 0, stream>>>(qb, kbuf);

    flash_k<<<dim3(S_ / 64, NH_, B_), tb, 0, stream>>>(qb, kbuf, vbuf, attn);

    gemm_bt_bias<true><<<gG, tb, 0, stream>>>(attn, WoT, bo, out, H_, H_);
}

// Round 3
// 709.762 us; speedup vs baseline: 1.0676x; 1.0676x over previous
//
#include <hip/hip_runtime.h>
#include <hip/hip_bf16.h>

#define B_ 2
#define S_ 2048
#define H_ 2048
#define NH_ 16
#define HD_ 128
#define M_ (B_*S_)   // 4096

typedef unsigned short u16;
typedef unsigned int u32;
typedef __attribute__((ext_vector_type(8))) short bhalf8_t;   // 8 bf16 in 4 VGPRs
typedef __attribute__((ext_vector_type(4))) float fx4_t;      // MFMA accumulator

__device__ __forceinline__ float bf2f(u16 v) {
    unsigned u = ((unsigned)v) << 16;
    return __builtin_bit_cast(float, u);
}
__device__ __forceinline__ u16 f2bf(float f) {
    unsigned u = __builtin_bit_cast(unsigned, f);
    unsigned r = u + 0x7fffu + ((u >> 16) & 1u);   // RNE
    return (u16)(r >> 16);
}
// async global->LDS, 16B per lane; dest = wave-uniform base + lane*16 (m97/m104)
__device__ __forceinline__ void gload_lds16(const u16* g, u16* l) {
    __builtin_amdgcn_global_load_lds(
        (const __attribute__((address_space(1))) u32*)g,
        (__attribute__((address_space(3))) u32*)l, 16, 0, 0);
}

// ---------------- fp32 -> bf16 elementwise convert ---------------------------
__global__ __launch_bounds__(256) void cvt_bf16_k(const float* __restrict__ in,
                                                  u16* __restrict__ out) {
    int i = blockIdx.x * 256 + threadIdx.x;      // one float4 per thread
    float4 v = ((const float4*)in)[i];
    ushort4 o;
    o.x = f2bf(v.x); o.y = f2bf(v.y); o.z = f2bf(v.z); o.w = f2bf(v.w);
    ((ushort4*)out)[i] = o;
}

// -------- weight transpose+convert: out_bf16[n][k] = in_f32[k][n], 2048x2048 --
__global__ __launch_bounds__(256) void transpose_cvt_k(const float* __restrict__ in,
                                                       u16* __restrict__ out) {
    __shared__ u16 tile[64][65];
    int k0 = blockIdx.y * 64, n0 = blockIdx.x * 64;
    int t = threadIdx.x;
    for (int i = 0; i < 16; i++) {
        int idx = t + i * 256;
        int r = idx >> 6, c = idx & 63;
        tile[r][c] = f2bf(in[(size_t)(k0 + r) * H_ + n0 + c]);
    }
    __syncthreads();
    for (int i = 0; i < 16; i++) {
        int idx = t + i * 256;
        int r = idx >> 6, c = idx & 63;
        out[(size_t)(n0 + r) * H_ + k0 + c] = tile[c][r];
    }
}

// ---------------- GEMM: C[M][N] = A[M][K] @ Bt[N][K]^T + bias[N] -------------
// 128x128 tile, 4 waves, mfma_f32_16x16x32_bf16, global_load_lds staging (m97).
// LDS tiles deliberately UNPADDED: global_load_lds needs lane-contiguous dest.
template <bool F32OUT>
__global__ __launch_bounds__(256) void gemm_bt_bias(const u16* __restrict__ A,
                                                    const u16* __restrict__ Bt,
                                                    const float* __restrict__ bias,
                                                    void* __restrict__ Cv,
                                                    int Nsz, int Ksz) {
    __shared__ u16 As[128][32];
    __shared__ u16 Bs[128][32];
    int t = threadIdx.x;
    int wave = t >> 6, lane = t & 63;
    int lr = lane & 15, lq = lane >> 4;
    int m0 = blockIdx.y * 128, n0 = blockIdx.x * 128;
    int wm = (wave >> 1) * 64, wn = (wave & 1) * 64;

    fx4_t acc[4][4];
    for (int i = 0; i < 4; i++)
        for (int j = 0; j < 4; j++)
            acc[i][j] = (fx4_t){0.f, 0.f, 0.f, 0.f};

    for (int k0 = 0; k0 < Ksz; k0 += 32) {
        for (int i = 0; i < 2; i++) {
            int chunk = t + i * 256;           // 512 chunks of 8 u16 = contiguous LDS
            int r = chunk >> 2, kc = (chunk & 3) * 8;
            gload_lds16(&A[(size_t)(m0 + r) * Ksz + k0 + kc], &As[0][0] + (size_t)chunk * 8);
            gload_lds16(&Bt[(size_t)(n0 + r) * Ksz + k0 + kc], &Bs[0][0] + (size_t)chunk * 8);
        }
        __syncthreads();
        bhalf8_t a[4], b[4];
        for (int i = 0; i < 4; i++) a[i] = *(const bhalf8_t*)&As[wm + i * 16 + lr][lq * 8];
        for (int j = 0; j < 4; j++) b[j] = *(const bhalf8_t*)&Bs[wn + j * 16 + lr][lq * 8];
        for (int i = 0; i < 4; i++)
            for (int j = 0; j < 4; j++)
                acc[i][j] = __builtin_amdgcn_mfma_f32_16x16x32_bf16(a[i], b[j], acc[i][j], 0, 0, 0);
        __syncthreads();
    }
    // C/D layout: row=(lane>>4)*4+reg, col=lane&15  [verified m89/m91]
    for (int i = 0; i < 4; i++)
        for (int j = 0; j < 4; j++) {
            int row = m0 + wm + i * 16 + lq * 4;
            int col = n0 + wn + j * 16 + lr;
            float bv = bias[col];
            for (int r = 0; r < 4; r++) {
                float v = acc[i][j][r] + bv;
                if (F32OUT)
                    ((float*)Cv)[(size_t)(row + r) * Nsz + col] = v;
                else
                    ((u16*)Cv)[(size_t)(row + r) * Nsz + col] = f2bf(v);
            }
        }
}

// ---------------- RoPE in-place on q and k ([B,S,NH,HD], bf16) ---------------
__global__ __launch_bounds__(256) void rope_k(u16* __restrict__ q, u16* __restrict__ k) {
    int idx = blockIdx.x * 256 + threadIdx.x;   // B*S*NH*64 threads
    int i = idx & 63;
    int n = (idx >> 6) & 15;
    int s = (idx >> 10) & 2047;
    int b = idx >> 21;
    float inv = 1.0f / powf(10000.0f, (float)i * (1.0f / 64.0f));
    float ang = (float)s * inv;
    float sn, c;
    sincosf(ang, &sn, &c);
    size_t base = ((size_t)(b * S_ + s) * NH_ + n) * HD_ + i;
    {
        float x1 = bf2f(q[base]), x2 = bf2f(q[base + 64]);
        q[base]      = f2bf(x1 * c - x2 * sn);
        q[base + 64] = f2bf(x2 * c + x1 * sn);
    }
    {
        float x1 = bf2f(k[base]), x2 = bf2f(k[base + 64]);
        k[base]      = f2bf(x1 * c - x2 * sn);
        k[base + 64] = f2bf(x2 * c + x1 * sn);
    }
}

// ---------------- flash attention, causal ------------------------------------
// block = (q-tile 64 rows, head, batch); 4 waves, each owns 16 q rows.
// Row pads (+8 u16 = 4 dwords) break the 16-way bank conflicts on b128 reads.
// Q fragments hoisted to registers; Ps aliases Qs -> 53.2 KB LDS -> 3 blocks/CU.
#define QROW 136   // 128+8
#define VROW 72    // 64+8
__global__ __launch_bounds__(256) void flash_k(const u16* __restrict__ qb,
                                               const u16* __restrict__ kb,
                                               const u16* __restrict__ vb,
                                               u16* __restrict__ attn) {
    __shared__ u16 sm[2 * 64 * QROW + 128 * VROW];
    u16* Qs = sm;                    // [64][QROW]; reused as Ps [64][VROW] after Q read
    u16* Ks = sm + 64 * QROW;        // [64][QROW]
    u16* Vt = sm + 2 * 64 * QROW;    // [128][VROW]  Vt[d][kpos]
    u16* Ps = sm;                    // alias of Qs

    int t = threadIdx.x, wave = t >> 6, lane = t & 63;
    int lr = lane & 15, lq = lane >> 4;
    int q0 = (gridDim.x - 1 - blockIdx.x) * 64;   // reversed: big causal tiles first
    int h = blockIdx.y, b = blockIdx.z;
    const float scale = 0.08838834764831845f;   // 1/sqrt(128)

    for (int i = 0; i < 4; i++) {
        int chunk = t + i * 256;
        int r = chunk >> 4, cg = (chunk & 15) * 8;
        *(bhalf8_t*)&Qs[r * QROW + cg] =
            *(const bhalf8_t*)&qb[((size_t)(b * S_ + q0 + r) * NH_ + h) * HD_ + cg];
    }
    __syncthreads();
    bhalf8_t aq[4];                  // loop-invariant Q fragments
    for (int ds = 0; ds < 4; ds++)
        aq[ds] = *(const bhalf8_t*)&Qs[(wave * 16 + lr) * QROW + ds * 32 + lq * 8];

    float m_i[4], l_i[4];
    fx4_t acc_o[8];
    for (int r = 0; r < 4; r++) { m_i[r] = -INFINITY; l_i[r] = 0.f; }
    for (int dt = 0; dt < 8; dt++) acc_o[dt] = (fx4_t){0.f, 0.f, 0.f, 0.f};

    int nkb = q0 / 64 + 1;           // causal: k-blocks 0..q-block inclusive
    for (int kb0 = 0; kb0 < nkb; kb0++) {
        int k0 = kb0 * 64;
        __syncthreads();   // prev iter's PV (and Qs->aq on iter 0) done before restaging
        for (int i = 0; i < 4; i++) {
            int chunk = t + i * 256;
            int r = chunk >> 4, cg = (chunk & 15) * 8;
            *(bhalf8_t*)&Ks[r * QROW + cg] =
                *(const bhalf8_t*)&kb[((size_t)(b * S_ + k0 + r) * NH_ + h) * HD_ + cg];
        }
        for (int i = 0; i < 4; i++) {
            int chunk = t + i * 256;
            int r = chunk & 63, d0 = (chunk >> 6) * 8;
            bhalf8_t vv =
                *(const bhalf8_t*)&vb[((size_t)(b * S_ + k0 + r) * NH_ + h) * HD_ + d0];
            for (int j = 0; j < 8; j++) Vt[(d0 + j) * VROW + r] = (u16)vv[j];
        }
        __syncthreads();

        // S = Q K^T for this wave's 16 rows x 64 cols
        fx4_t sacc[4];
        for (int nt = 0; nt < 4; nt++) sacc[nt] = (fx4_t){0.f, 0.f, 0.f, 0.f};
        for (int nt = 0; nt < 4; nt++)
            for (int ds = 0; ds < 4; ds++) {
                bhalf8_t bk = *(const bhalf8_t*)&Ks[(nt * 16 + lr) * QROW + ds * 32 + lq * 8];
                sacc[nt] = __builtin_amdgcn_mfma_f32_16x16x32_bf16(aq[ds], bk, sacc[nt], 0, 0, 0);
            }

        // online softmax (fp32). lane holds rows lq*4+r, cols nt*16+lr.
        float sv[4][4];
        for (int nt = 0; nt < 4; nt++)
            for (int r = 0; r < 4; r++) {
                float x = sacc[nt][r] * scale;
                int kpos = k0 + nt * 16 + lr;
                int qpos = q0 + wave * 16 + lq * 4 + r;
                if (kpos > qpos) x -= 1e9f;
                sv[nt][r] = x;
            }
        float rmax[4], alpha[4], rsum[4];
        for (int r = 0; r < 4; r++)
            rmax[r] = fmaxf(fmaxf(sv[0][r], sv[1][r]), fmaxf(sv[2][r], sv[3][r]));
        for (int off = 1; off < 16; off <<= 1)
            for (int r = 0; r < 4; r++)
                rmax[r] = fmaxf(rmax[r], __shfl_xor(rmax[r], off, 64));
        for (int r = 0; r < 4; r++) {
            float mn = fmaxf(m_i[r], rmax[r]);
            alpha[r] = __expf(m_i[r] - mn);
            m_i[r] = mn;
            float s4 = 0.f;
            for (int nt = 0; nt < 4; nt++) {
                float p = __expf(sv[nt][r] - mn);
                sv[nt][r] = p;
                s4 += p;
            }
            rsum[r] = s4;
        }
        for (int off = 1; off < 16; off <<= 1)
            for (int r = 0; r < 4; r++)
                rsum[r] += __shfl_xor(rsum[r], off, 64);
        for (int r = 0; r < 4; r++) l_i[r] = l_i[r] * alpha[r] + rsum[r];
        for (int dt = 0; dt < 8; dt++)
            for (int r = 0; r < 4; r++) acc_o[dt][r] *= alpha[r];

        // P (C-layout) -> LDS -> A-layout for PV
        for (int nt = 0; nt < 4; nt++)
            for (int r = 0; r < 4; r++)
                Ps[(wave * 16 + lq * 4 + r) * VROW + nt * 16 + lr] = f2bf(sv[nt][r]);
        __syncthreads();

        for (int ds = 0; ds < 2; ds++) {
            bhalf8_t ap = *(const bhalf8_t*)&Ps[(wave * 16 + lr) * VROW + ds * 32 + lq * 8];
            for (int dt = 0; dt < 8; dt++) {
                bhalf8_t bv = *(const bhalf8_t*)&Vt[(dt * 16 + lr) * VROW + ds * 32 + lq * 8];
                acc_o[dt] = __builtin_amdgcn_mfma_f32_16x16x32_bf16(ap, bv, acc_o[dt], 0, 0, 0);
            }
        }
    }
    for (int dt = 0; dt < 8; dt++)
        for (int r = 0; r < 4; r++) {
            size_t row = (size_t)(b * S_ + q0 + wave * 16 + lq * 4 + r);
            attn[(row * NH_ + h) * HD_ + dt * 16 + lr] = f2bf(acc_o[dt][r] / l_i[r]);
        }
}

extern "C" void kernel_launch(void* const* d_in, const int* in_sizes, int n_in,
                              void* d_out, int out_size, void* d_ws, size_t ws_size,
                              hipStream_t stream) {
    const float* hs = (const float*)d_in[0];
    // d_in[1] = mask (causal triu) — hard-coded in flash_k
    const float* Wq = (const float*)d_in[2];
    const float* bq = (const float*)d_in[3];
    const float* Wk = (const float*)d_in[4];
    const float* bk = (const float*)d_in[5];
    const float* Wv = (const float*)d_in[6];
    const float* bv = (const float*)d_in[7];
    const float* Wo = (const float*)d_in[8];
    const float* bo = (const float*)d_in[9];
    float* out = (float*)d_out;

    u16* ws   = (u16*)d_ws;
    size_t WW = (size_t)H_ * H_;       // 4.19M elems
    size_t AC = (size_t)M_ * H_;       // 8.39M elems
    u16* hsb  = ws;
    u16* WqT  = hsb + AC;
    u16* WkT  = WqT + WW;
    u16* WvT  = WkT + WW;
    u16* WoT  = WvT + WW;
    u16* qb   = WoT + WW;
    u16* kbuf = qb + AC;
    u16* vbuf = kbuf + AC;
    u16* attn = vbuf + AC;

    dim3 tb(256);

    cvt_bf16_k<<<dim3(AC / (256 * 4)), tb, 0, stream>>>(hs, hsb);

    dim3 gT(32, 32);
    transpose_cvt_k<<<gT, tb, 0, stream>>>(Wq, WqT);
    transpose_cvt_k<<<gT, tb, 0, stream>>>(Wk, WkT);
    transpose_cvt_k<<<gT, tb, 0, stream>>>(Wv, WvT);
    transpose_cvt_k<<<gT, tb, 0, stream>>>(Wo, WoT);

    dim3 gG(H_ / 128, M_ / 128);       // (16, 32)
    gemm_bt_bias<false><<<gG, tb, 0, stream>>>(hsb, WqT, bq, qb, H_, H_);
    gemm_bt_bias<false><<<gG, tb, 0, stream>>>(hsb, WkT, bk, kbuf, H_, H_);
    gemm_bt_bias<false><<<gG, tb, 0, stream>>>(hsb, WvT, bv, vbuf, H_, H_);

    rope_k<<<dim3((B_ * S_ * NH_ * 64) / 256), tb, 0, stream>>>(qb, kbuf);

    flash_k<<<dim3(S_ / 64, NH_, B_), tb, 0, stream>>>(qb, kbuf, vbuf, attn);

    gemm_bt_bias<true><<<gG, tb, 0, stream>>>(attn, WoT, bo, out, H_, H_);
}

// Round 4
// 523.570 us; speedup vs baseline: 1.4472x; 1.3556x over previous
//
#include <hip/hip_runtime.h>
#include <hip/hip_bf16.h>

#define B_ 2
#define S_ 2048
#define H_ 2048
#define NH_ 16
#define HD_ 128
#define M_ (B_*S_)   // 4096

typedef unsigned short u16;
typedef unsigned int u32;
typedef __attribute__((ext_vector_type(8))) short bhalf8_t;   // 8 bf16 in 4 VGPRs
typedef __attribute__((ext_vector_type(4))) float fx4_t;      // MFMA accumulator

__device__ __forceinline__ float bf2f(u16 v) {
    unsigned u = ((unsigned)v) << 16;
    return __builtin_bit_cast(float, u);
}
__device__ __forceinline__ u16 f2bf(float f) {
    unsigned u = __builtin_bit_cast(unsigned, f);
    unsigned r = u + 0x7fffu + ((u >> 16) & 1u);   // RNE
    return (u16)(r >> 16);
}
// async global->LDS, 16B/lane; LDS dest must be lane-linear (m104). Global side
// is a gather -> we XOR-swizzle the GLOBAL source so LDS ends up swizzled.
__device__ __forceinline__ void gload_lds16(const u16* g, u16* l) {
    __builtin_amdgcn_global_load_lds(
        (const __attribute__((address_space(1))) u32*)g,
        (__attribute__((address_space(3))) u32*)l, 16, 0, 0);
}

// ---------------- fp32 -> bf16 elementwise convert ---------------------------
__global__ __launch_bounds__(256) void cvt_bf16_k(const float* __restrict__ in,
                                                  u16* __restrict__ out) {
    int i = blockIdx.x * 256 + threadIdx.x;
    float4 v = ((const float4*)in)[i];
    ushort4 o;
    o.x = f2bf(v.x); o.y = f2bf(v.y); o.z = f2bf(v.z); o.w = f2bf(v.w);
    ((ushort4*)out)[i] = o;
}

// -------- weight transpose+convert: out_bf16[n][k] = in_f32[k][n], 2048x2048 --
__global__ __launch_bounds__(256) void transpose_cvt_k(const float* __restrict__ in,
                                                       u16* __restrict__ out) {
    __shared__ u16 tile[64][65];
    int k0 = blockIdx.y * 64, n0 = blockIdx.x * 64;
    int t = threadIdx.x;
    for (int i = 0; i < 16; i++) {
        int idx = t + i * 256;
        int r = idx >> 6, c = idx & 63;
        tile[r][c] = f2bf(in[(size_t)(k0 + r) * H_ + n0 + c]);
    }
    __syncthreads();
    for (int i = 0; i < 16; i++) {
        int idx = t + i * 256;
        int r = idx >> 6, c = idx & 63;
        out[(size_t)(n0 + r) * H_ + k0 + c] = tile[c][r];
    }
}

// ---------------- GEMM: C[M][N] = A[M][K] @ Bt[N][K]^T + bias[N] -------------
// 128x128 tile, BK=64, XOR-swizzled LDS, global_load_lds staging.
// OUTMODE: 0 = bf16 [M][N]; 1 = fp32 [M][N]; 2 = bf16 V^T [b,h,d,s]
template <int OUTMODE>
__global__ __launch_bounds__(256) void gemm_bt_bias(const u16* __restrict__ A,
                                                    const u16* __restrict__ Bt,
                                                    const float* __restrict__ bias,
                                                    void* __restrict__ Cv,
                                                    int Nsz, int Ksz) {
    __shared__ u16 As[128 * 64];
    __shared__ u16 Bs[128 * 64];
    int t = threadIdx.x;
    int wave = t >> 6, lane = t & 63;
    int lr = lane & 15, lq = lane >> 4;
    int m0 = blockIdx.y * 128, n0 = blockIdx.x * 128;
    int wm = (wave >> 1) * 64, wn = (wave & 1) * 64;

    fx4_t acc[4][4];
    for (int i = 0; i < 4; i++)
        for (int j = 0; j < 4; j++)
            acc[i][j] = (fx4_t){0.f, 0.f, 0.f, 0.f};

    for (int k0 = 0; k0 < Ksz; k0 += 64) {
        for (int i = 0; i < 4; i++) {
            int c = t + i * 256;               // 1024 chunks of 16B per tile
            int r = c >> 3, g = (c & 7) ^ (r & 7);
            gload_lds16(&A[(size_t)(m0 + r) * Ksz + k0 + g * 8], As + (size_t)c * 8);
            gload_lds16(&Bt[(size_t)(n0 + r) * Ksz + k0 + g * 8], Bs + (size_t)c * 8);
        }
        __syncthreads();
        for (int ds = 0; ds < 2; ds++) {
            bhalf8_t a[4], b[4];
            int cs = (ds * 4 + lq) ^ (lr & 7);
            for (int i = 0; i < 4; i++)
                a[i] = *(const bhalf8_t*)&As[(((wm + i * 16 + lr) << 3) + cs) * 8];
            for (int j = 0; j < 4; j++)
                b[j] = *(const bhalf8_t*)&Bs[(((wn + j * 16 + lr) << 3) + cs) * 8];
            for (int i = 0; i < 4; i++)
                for (int j = 0; j < 4; j++)
                    acc[i][j] = __builtin_amdgcn_mfma_f32_16x16x32_bf16(a[i], b[j], acc[i][j], 0, 0, 0);
        }
        __syncthreads();
    }
    // C/D layout: row=(lane>>4)*4+reg, col=lane&15
    for (int i = 0; i < 4; i++)
        for (int j = 0; j < 4; j++) {
            int row0 = m0 + wm + i * 16 + lq * 4;
            int col = n0 + wn + j * 16 + lr;
            float bv = bias[col];
            if (OUTMODE == 2) {
                int bb = row0 >> 11, s = row0 & 2047;
                int hh = col >> 7, d = col & 127;
                ushort4 w;
                w.x = f2bf(acc[i][j][0] + bv);
                w.y = f2bf(acc[i][j][1] + bv);
                w.z = f2bf(acc[i][j][2] + bv);
                w.w = f2bf(acc[i][j][3] + bv);
                *(ushort4*)&((u16*)Cv)[(((size_t)bb * NH_ + hh) * HD_ + d) * S_ + s] = w;
            } else {
                for (int r = 0; r < 4; r++) {
                    float v = acc[i][j][r] + bv;
                    if (OUTMODE == 1)
                        ((float*)Cv)[(size_t)(row0 + r) * Nsz + col] = v;
                    else
                        ((u16*)Cv)[(size_t)(row0 + r) * Nsz + col] = f2bf(v);
                }
            }
        }
}

// ---------------- RoPE in-place on q and k ([B,S,NH,HD], bf16) ---------------
__global__ __launch_bounds__(256) void rope_k(u16* __restrict__ q, u16* __restrict__ k) {
    int idx = blockIdx.x * 256 + threadIdx.x;
    int i = idx & 63;
    int n = (idx >> 6) & 15;
    int s = (idx >> 10) & 2047;
    int b = idx >> 21;
    float inv = 1.0f / powf(10000.0f, (float)i * (1.0f / 64.0f));
    float ang = (float)s * inv;
    float sn, c;
    sincosf(ang, &sn, &c);
    size_t base = ((size_t)(b * S_ + s) * NH_ + n) * HD_ + i;
    {
        float x1 = bf2f(q[base]), x2 = bf2f(q[base + 64]);
        q[base]      = f2bf(x1 * c - x2 * sn);
        q[base + 64] = f2bf(x2 * c + x1 * sn);
    }
    {
        float x1 = bf2f(k[base]), x2 = bf2f(k[base + 64]);
        k[base]      = f2bf(x1 * c - x2 * sn);
        k[base + 64] = f2bf(x2 * c + x1 * sn);
    }
}

// ---------------- flash attention, causal, software-pipelined ----------------
// block = (q-tile 64 rows, head, batch); 4 waves x 16 q-rows.
// K/V double-buffered in LDS via global_load_lds (XOR-swizzled global source);
// next tile's loads issue right after the single per-iter barrier.
// Ps is wave-private -> lgkmcnt-only sync. Row-sum fused into PV as ones-MFMA.
#define PROW 72
__global__ __launch_bounds__(256) void flash_k(const u16* __restrict__ qb,
                                               const u16* __restrict__ kb,
                                               const u16* __restrict__ vT,
                                               u16* __restrict__ attn) {
    __shared__ u16 sm[4 * 8192 + 64 * PROW];   // Ks x2 | Vt x2 | Ps  (74.75 KB)
    u16* KsB = sm;            // [buf][64 rows][16 chunks]
    u16* VtB = sm + 16384;    // [buf][128 rows][8 chunks]
    u16* Ps  = sm + 32768;    // [64][PROW]

    int t = threadIdx.x, wave = t >> 6, lane = t & 63;
    int lr = lane & 15, lq = lane >> 4;
    int q0 = (int)(gridDim.x - 1 - blockIdx.x) * 64;   // big causal tiles first
    int h = blockIdx.y, b = blockIdx.z;
    const float scale = 0.08838834764831845f;   // 1/sqrt(128)

    // Q fragments loaded once, directly from global (A-layout)
    bhalf8_t aq[4];
    {
        size_t qrow = ((size_t)(b * S_ + q0 + wave * 16 + lr) * NH_ + h) * HD_;
        for (int ds = 0; ds < 4; ds++)
            aq[ds] = *(const bhalf8_t*)&qb[qrow + ds * 32 + lq * 8];
    }

    float m_i[4], l_i[4];
    fx4_t acc_o[8];
    for (int r = 0; r < 4; r++) { m_i[r] = -INFINITY; l_i[r] = 0.f; }
    for (int dt = 0; dt < 8; dt++) acc_o[dt] = (fx4_t){0.f, 0.f, 0.f, 0.f};

    bhalf8_t bones;
    for (int j = 0; j < 8; j++) bones[j] = (short)0x3F80;   // bf16 1.0

    int nkb = q0 / 64 + 1;

    // ---- staging (issue-only; completion enforced by barrier vmcnt drain) ----
    auto stageK = [&](int buf, int k0) {
        u16* dst = KsB + buf * 8192;
        for (int i = 0; i < 4; i++) {
            int c = t + i * 256;               // 64 rows x 16 chunks
            int r = c >> 4, g = (c & 15) ^ (r & 15);
            gload_lds16(&kb[((size_t)(b * S_ + k0 + r) * NH_ + h) * HD_ + g * 8],
                        dst + (size_t)c * 8);
        }
    };
    auto stageV = [&](int buf, int k0) {
        u16* dst = VtB + buf * 8192;
        for (int i = 0; i < 4; i++) {
            int c = t + i * 256;               // 128 rows x 8 chunks
            int r = c >> 3, g = (c & 7) ^ (r & 7);
            gload_lds16(&vT[((size_t)(b * NH_ + h) * HD_ + r) * S_ + k0 + g * 8],
                        dst + (size_t)c * 8);
        }
    };

    stageK(0, 0);
    stageV(0, 0);
    for (int kbi = 0; kbi < nkb; kbi++) {
        int cur = kbi & 1;
        int k0 = kbi * 64;
        __syncthreads();   // drains buf[cur] loads; all waves off buf[cur^1]
        if (kbi + 1 < nkb) { stageK(cur ^ 1, k0 + 64); stageV(cur ^ 1, k0 + 64); }
        const u16* Kc = KsB + cur * 8192;
        const u16* Vc = VtB + cur * 8192;

        // S = Q K^T : this wave's 16 rows x 64 cols
        fx4_t sacc[4];
        for (int nt = 0; nt < 4; nt++) sacc[nt] = (fx4_t){0.f, 0.f, 0.f, 0.f};
        for (int nt = 0; nt < 4; nt++) {
            int r = nt * 16 + lr;
            for (int ds = 0; ds < 4; ds++) {
                bhalf8_t bk = *(const bhalf8_t*)&Kc[((r << 4) + ((ds * 4 + lq) ^ lr)) * 8];
                sacc[nt] = __builtin_amdgcn_mfma_f32_16x16x32_bf16(aq[ds], bk, sacc[nt], 0, 0, 0);
            }
        }

        // online softmax (fp32); lane holds rows lq*4+r, cols nt*16+lr
        float sv[4][4];
        for (int nt = 0; nt < 4; nt++)
            for (int r = 0; r < 4; r++) {
                float x = sacc[nt][r] * scale;
                int kpos = k0 + nt * 16 + lr;
                int qpos = q0 + wave * 16 + lq * 4 + r;
                if (kpos > qpos) x -= 1e9f;
                sv[nt][r] = x;
            }
        float rmax[4], alpha[4];
        for (int r = 0; r < 4; r++)
            rmax[r] = fmaxf(fmaxf(sv[0][r], sv[1][r]), fmaxf(sv[2][r], sv[3][r]));
        for (int off = 1; off < 16; off <<= 1)
            for (int r = 0; r < 4; r++)
                rmax[r] = fmaxf(rmax[r], __shfl_xor(rmax[r], off, 64));
        for (int r = 0; r < 4; r++) {
            float mn = fmaxf(m_i[r], rmax[r]);
            alpha[r] = __expf(m_i[r] - mn);
            m_i[r] = mn;
            for (int nt = 0; nt < 4; nt++)
                sv[nt][r] = __expf(sv[nt][r] - mn);
            l_i[r] *= alpha[r];
        }
        for (int dt = 0; dt < 8; dt++)
            for (int r = 0; r < 4; r++) acc_o[dt][r] *= alpha[r];

        // P (C-layout) -> LDS (wave-private rows) -> A-layout
        for (int nt = 0; nt < 4; nt++)
            for (int r = 0; r < 4; r++)
                Ps[(wave * 16 + lq * 4 + r) * PROW + nt * 16 + lr] = f2bf(sv[nt][r]);
        __asm__ volatile("s_waitcnt lgkmcnt(0)" ::: "memory");  // wave-local sync

        // O += P V ; row-sum via ones-MFMA (l-update deferred -> same algebra)
        fx4_t ls = (fx4_t){0.f, 0.f, 0.f, 0.f};
        for (int ds = 0; ds < 2; ds++) {
            bhalf8_t ap = *(const bhalf8_t*)&Ps[(wave * 16 + lr) * PROW + ds * 32 + lq * 8];
            for (int dt = 0; dt < 8; dt++) {
                int r = dt * 16 + lr;
                bhalf8_t bv = *(const bhalf8_t*)&Vc[((r << 3) + ((ds * 4 + lq) ^ (lr & 7))) * 8];
                acc_o[dt] = __builtin_amdgcn_mfma_f32_16x16x32_bf16(ap, bv, acc_o[dt], 0, 0, 0);
            }
            ls = __builtin_amdgcn_mfma_f32_16x16x32_bf16(ap, bones, ls, 0, 0, 0);
        }
        for (int r = 0; r < 4; r++) l_i[r] += ls[r];
    }

    for (int dt = 0; dt < 8; dt++)
        for (int r = 0; r < 4; r++) {
            size_t row = (size_t)(b * S_ + q0 + wave * 16 + lq * 4 + r);
            attn[(row * NH_ + h) * HD_ + dt * 16 + lr] = f2bf(acc_o[dt][r] / l_i[r]);
        }
}

extern "C" void kernel_launch(void* const* d_in, const int* in_sizes, int n_in,
                              void* d_out, int out_size, void* d_ws, size_t ws_size,
                              hipStream_t stream) {
    const float* hs = (const float*)d_in[0];
    // d_in[1] = mask (causal triu) — hard-coded in flash_k
    const float* Wq = (const float*)d_in[2];
    const float* bq = (const float*)d_in[3];
    const float* Wk = (const float*)d_in[4];
    const float* bk = (const float*)d_in[5];
    const float* Wv = (const float*)d_in[6];
    const float* bv = (const float*)d_in[7];
    const float* Wo = (const float*)d_in[8];
    const float* bo = (const float*)d_in[9];
    float* out = (float*)d_out;

    u16* ws   = (u16*)d_ws;
    size_t WW = (size_t)H_ * H_;
    size_t AC = (size_t)M_ * H_;
    u16* hsb  = ws;
    u16* WqT  = hsb + AC;
    u16* WkT  = WqT + WW;
    u16* WvT  = WkT + WW;
    u16* WoT  = WvT + WW;
    u16* qb   = WoT + WW;
    u16* kbuf = qb + AC;
    u16* vTb  = kbuf + AC;     // V in [b,h,d,s] layout
    u16* attn = vTb + AC;

    dim3 tb(256);

    cvt_bf16_k<<<dim3(AC / (256 * 4)), tb, 0, stream>>>(hs, hsb);

    dim3 gT(32, 32);
    transpose_cvt_k<<<gT, tb, 0, stream>>>(Wq, WqT);
    transpose_cvt_k<<<gT, tb, 0, stream>>>(Wk, WkT);
    transpose_cvt_k<<<gT, tb, 0, stream>>>(Wv, WvT);
    transpose_cvt_k<<<gT, tb, 0, stream>>>(Wo, WoT);

    dim3 gG(H_ / 128, M_ / 128);       // (16, 32)
    gemm_bt_bias<0><<<gG, tb, 0, stream>>>(hsb, WqT, bq, qb, H_, H_);
    gemm_bt_bias<0><<<gG, tb, 0, stream>>>(hsb, WkT, bk, kbuf, H_, H_);
    gemm_bt_bias<2><<<gG, tb, 0, stream>>>(hsb, WvT, bv, vTb, H_, H_);

    rope_k<<<dim3((B_ * S_ * NH_ * 64) / 256), tb, 0, stream>>>(qb, kbuf);

    flash_k<<<dim3(S_ / 64, NH_, B_), tb, 0, stream>>>(qb, kbuf, vTb, attn);

    gemm_bt_bias<1><<<gG, tb, 0, stream>>>(attn, WoT, bo, out, H_, H_);
}